// Round 4
// baseline (235.681 us; speedup 1.0000x reference)
//
#include <hip/hip_runtime.h>
#include <hip/hip_bf16.h>
#include <cstdint>
#include <cstddef>

// Problem constants (fixed shapes per reference)
#define NROWS 8192
#define DIM   1024
#define BM 128
#define BN 128
#define BK 32            // per-buffer K depth; double-buffered (2 x 8KB x 2 tiles = 32KB)
#define INV_T 10.0f
#define EPS 1e-8f

typedef short  bf16x8  __attribute__((ext_vector_type(8)));
typedef float  floatx4 __attribute__((ext_vector_type(4)));

typedef __attribute__((address_space(1))) const void CGV;
typedef __attribute__((address_space(3))) void LV;

__device__ __forceinline__ void async_load16(const void* g, void* l) {
    __builtin_amdgcn_global_load_lds((CGV*)g, (LV*)l, 16, 0, 0);
}

__device__ __forceinline__ unsigned short f2bf_rne(float f) {
    union { float f; unsigned u; } c; c.f = f;
    unsigned u = c.u;
    unsigned r = (u + 0x7fffu + ((u >> 16) & 1u)) >> 16;
    return (unsigned short)r;
}

// ---------------------------------------------------------------------------
// Kernel A: fp32 -> bf16 (RNE), vectorized. First 64 blocks also zero the
// 16384-float accumulator region (replaces a separate memset dispatch).
// ---------------------------------------------------------------------------
__global__ __launch_bounds__(256) void convert_kernel(
    const float* __restrict__ in, unsigned short* __restrict__ out,
    float* __restrict__ accum /* all_sum ++ pos_sum, 2*NROWS floats */)
{
    int i = (blockIdx.x * 256 + threadIdx.x) * 4;
    float4 v = *(const float4*)(in + i);
    ushort4 o;
    o.x = f2bf_rne(v.x);
    o.y = f2bf_rne(v.y);
    o.z = f2bf_rne(v.z);
    o.w = f2bf_rne(v.w);
    *(ushort4*)(out + i) = o;
    if (blockIdx.x < (2 * NROWS) / 256)
        accum[blockIdx.x * 256 + threadIdx.x] = 0.0f;
}

// ---------------------------------------------------------------------------
// Kernel B: symmetric-half fused GEMM, single-barrier double-buffered K-loop.
// Loads for iteration i+1 are issued into buf[1-cur] right after the barrier
// (race-free: all waves finished reading that buffer before the barrier) and
// before compute i, so the vmcnt drain at barrier i+1 finds them landed.
// LDS chunk swizzle c' = c ^ ((row>>1)&3): quad b128 reads hit all 8
// bank-groups, 2 lanes each (free). Off-diagonal tiles feed row- AND
// col-reduces (symmetry); diagonal tiles mask j==i.
// ---------------------------------------------------------------------------
__global__ __launch_bounds__(256, 4) void gemm_fused_kernel(
    const unsigned short* __restrict__ E,   // bf16 bits, row-major [NROWS][DIM]
    const int*            __restrict__ labels,
    float*                __restrict__ all_sum,
    float*                __restrict__ pos_sum)
{
    __shared__ __align__(16) unsigned short sA[2][BM * BK];   // 2 x 8 KB
    __shared__ __align__(16) unsigned short sB[2][BN * BK];   // 2 x 8 KB

    const int tid  = threadIdx.x;
    const int lane = tid & 63;
    const int w    = tid >> 6;
    const int wm   = w >> 1;        // wave row (0..1) -> 64 rows
    const int wn   = w & 1;         // wave col (0..1) -> 64 cols
    const int colw = lane & 15;
    const int quad = lane >> 4;

    // decode lower-triangle pair: t -> (bi, bj), bj <= bi
    const int t = blockIdx.x;
    int bi = (int)((sqrtf(8.0f * (float)t + 1.0f) - 1.0f) * 0.5f);
    while ((bi + 1) * (bi + 2) / 2 <= t) ++bi;
    while (bi * (bi + 1) / 2 > t) --bi;
    const int bj = t - bi * (bi + 1) / 2;

    const int rBase = bi * BM;      // rows (A tile)
    const int cBase = bj * BN;      // cols (B tile)
    const bool diag = (bi == bj);

    // Staging: tile = 128x32 elems = 512 chunks of 16B. Thread t stages chunks
    // t (row t>>2) and t+256 (row +64) per tile. Swizzled column placement:
    // global chunk c = (t&3) ^ ((row>>1)&3); (row>>1)&3 invariant under +64.
    const int srow = tid >> 2;
    const int scol = (((tid & 3) ^ ((tid >> 3) & 3)) << 3);  // elem col 0..31
    const int e0   = tid * 8;                                // LDS elem offset

    floatx4 acc[4][4];
    #pragma unroll
    for (int i = 0; i < 4; ++i)
        #pragma unroll
        for (int j = 0; j < 4; ++j)
            acc[i][j] = (floatx4)0.0f;

    // Fragment reads: row = {wm,wn}*64 + mt*16 + colw; chunk for quad q stored
    // at q ^ ((row>>1)&3) = q ^ ((colw>>1)&3)  (mt*16, wm*64 drop out).
    const int swz   = (colw >> 1) & 3;
    const int cOff  = ((quad ^ swz) << 3);
    const int aRow0 = (wm * 64 + colw) * BK;
    const int bRow0 = (wn * 64 + colw) * BK;

    const size_t gA0 = (size_t)(rBase + srow) * DIM + scol;
    const size_t gB0 = (size_t)(cBase + srow) * DIM + scol;
    const size_t rstep = (size_t)64 * DIM;

    // prologue: stage k0=0 into buffer 0
    async_load16(E + gA0,         &sA[0][e0]);
    async_load16(E + gA0 + rstep, &sA[0][e0 + 2048]);
    async_load16(E + gB0,         &sB[0][e0]);
    async_load16(E + gB0 + rstep, &sB[0][e0 + 2048]);

    #pragma unroll 2
    for (int it = 0; it < DIM / BK; ++it) {
        const int cur = it & 1;
        __syncthreads();   // drains loads into buf[cur] (issued a full compute phase ago)
        if (it + 1 < DIM / BK) {
            const size_t kOff = (size_t)(it + 1) * BK;
            async_load16(E + gA0 + kOff,         &sA[1 - cur][e0]);
            async_load16(E + gA0 + rstep + kOff, &sA[1 - cur][e0 + 2048]);
            async_load16(E + gB0 + kOff,         &sB[1 - cur][e0]);
            async_load16(E + gB0 + rstep + kOff, &sB[1 - cur][e0 + 2048]);
        }

        bf16x8 aF[4], bF[4];
        #pragma unroll
        for (int mt = 0; mt < 4; ++mt)
            aF[mt] = *(const bf16x8*)&sA[cur][aRow0 + mt * 16 * BK + cOff];
        #pragma unroll
        for (int nt = 0; nt < 4; ++nt)
            bF[nt] = *(const bf16x8*)&sB[cur][bRow0 + nt * 16 * BK + cOff];

        #pragma unroll
        for (int mt = 0; mt < 4; ++mt)
            #pragma unroll
            for (int nt = 0; nt < 4; ++nt)
                acc[mt][nt] = __builtin_amdgcn_mfma_f32_16x16x32_bf16(
                    aF[mt], bF[nt], acc[mt][nt], 0, 0, 0);
    }

    // Epilogue. C/D layout (16x16x32): col = lane&15, row = quad*4 + reg.
    float labc[4];
    int   gcol[4];
    #pragma unroll
    for (int nt = 0; nt < 4; ++nt) {
        gcol[nt] = cBase + wn * 64 + nt * 16 + colw;
        labc[nt] = (float)labels[gcol[nt]];
    }

    float colAll[4] = {0.f, 0.f, 0.f, 0.f};
    float colPos[4] = {0.f, 0.f, 0.f, 0.f};

    #pragma unroll
    for (int mt = 0; mt < 4; ++mt) {
        const int growBase = rBase + wm * 64 + mt * 16 + quad * 4;
        #pragma unroll
        for (int r = 0; r < 4; ++r) {
            const int grow = growBase + r;
            const float labr = (float)labels[grow];
            float sAll = 0.f, sPos = 0.f;
            #pragma unroll
            for (int nt = 0; nt < 4; ++nt) {
                float ev = __expf(acc[mt][nt][r] * INV_T);
                if (diag && grow == gcol[nt]) ev = 0.0f;  // exclude self
                sAll += ev;
                sPos += ev * labc[nt];
                colAll[nt] += ev;
                colPos[nt] += ev * labr;
            }
            // row-reduce across the 16 lanes (same quad) sharing this row
            #pragma unroll
            for (int off = 1; off < 16; off <<= 1) {
                sAll += __shfl_xor(sAll, off);
                sPos += __shfl_xor(sPos, off);
            }
            if (colw == 0) {
                atomicAdd(&all_sum[grow], sAll);
                atomicAdd(&pos_sum[grow], sPos);
            }
        }
    }

    if (!diag) {
        // col-reduce: sum across quads (lanes differing in bits 4,5)
        #pragma unroll
        for (int nt = 0; nt < 4; ++nt) {
            float a = colAll[nt], p = colPos[nt];
            a += __shfl_xor(a, 16);  p += __shfl_xor(p, 16);
            a += __shfl_xor(a, 32);  p += __shfl_xor(p, 32);
            if (quad == 0) {
                atomicAdd(&all_sum[gcol[nt]], a);
                atomicAdd(&pos_sum[gcol[nt]], p);
            }
        }
    }
}

// ---------------------------------------------------------------------------
// Kernel C: loss = mean over rows with lab==1 of -log(pos/(all+eps)); 0 if n_ref<2
// ---------------------------------------------------------------------------
__global__ __launch_bounds__(1024) void finalize_kernel(
    const float* __restrict__ all_sum,
    const float* __restrict__ pos_sum,
    const int*   __restrict__ labels,
    float*       __restrict__ out)
{
    __shared__ float sSum[1024];
    __shared__ float sCnt[1024];
    const int tid = threadIdx.x;
    float lsum = 0.f, lcnt = 0.f;
    for (int i = tid; i < NROWS; i += 1024) {
        if (labels[i] > 0) {
            float p = pos_sum[i];
            float a = all_sum[i] + EPS;
            lsum += -logf(p / a);
            lcnt += 1.0f;
        }
    }
    sSum[tid] = lsum;
    sCnt[tid] = lcnt;
    __syncthreads();
    for (int s = 512; s > 0; s >>= 1) {
        if (tid < s) { sSum[tid] += sSum[tid + s]; sCnt[tid] += sCnt[tid + s]; }
        __syncthreads();
    }
    if (tid == 0) {
        float n = sCnt[0];
        out[0] = (n < 2.0f) ? 0.0f : sSum[0] / fmaxf(n, 1.0f);
    }
}

// ---------------------------------------------------------------------------
extern "C" void kernel_launch(void* const* d_in, const int* in_sizes, int n_in,
                              void* d_out, int out_size, void* d_ws, size_t ws_size,
                              hipStream_t stream) {
    const float* emb    = (const float*)d_in[0];
    const int*   labels = (const int*)d_in[1];
    float*       out    = (float*)d_out;

    // workspace layout: [bf16 E: 16 MB][all_sum: 32 KB][pos_sum: 32 KB]
    unsigned short* Ebf = (unsigned short*)d_ws;
    const size_t embBytes = (size_t)NROWS * DIM * sizeof(unsigned short);
    float* all_sum = (float*)((char*)d_ws + embBytes);
    float* pos_sum = all_sum + NROWS;

    convert_kernel<<<(NROWS * DIM) / (4 * 256), 256, 0, stream>>>(emb, Ebf, all_sum);

    const int nBlocksTri = (NROWS / BM) * (NROWS / BM + 1) / 2;  // 64*65/2 = 2080
    gemm_fused_kernel<<<nBlocksTri, 256, 0, stream>>>(Ebf, labels, all_sum, pos_sum);

    finalize_kernel<<<1, 1024, 0, stream>>>(all_sum, pos_sum, labels, out);
}